// Round 3
// baseline (263.291 us; speedup 1.0000x reference)
//
#include <hip/hip_runtime.h>
#include <math.h>

// Problem constants (from reference)
#define BB 64
#define TT 8192
#define NH 8
#define HD 10
#define DD 80            // NH*HD floats per (b,t) row
#define NCHUNK 32        // K1: T-chunks per b (TT/256)
// ks scale: (1/sqrt(10)) * 2*log2(e)  -> makes ex = exp2(-|q*ks2|) == e^{-2|s|}
#define KSCALE 0.9123740929154171f
#define LOG2E  1.4426950408889634f

// ---------------------------------------------------------------------------
// K1: per-(b,chunk) partial column sums of x, race-free.
// gpart[(b*32+chunk)*80 + d] = sum over the chunk's 256 rows of x[b][t][d].
// 2048 blocks x 320 threads; each wave's loads are 1KB contiguous.
// ---------------------------------------------------------------------------
__global__ __launch_bounds__(320) void ksum_kernel(const float* __restrict__ x,
                                                   float* __restrict__ gpart) {
    int chunk = blockIdx.x & (NCHUNK - 1);
    int b     = blockIdx.x >> 5;
    const float4* xp = (const float4*)(x + ((size_t)b * TT + (size_t)chunk * 256) * DD);

    int tid = threadIdx.x;
    int c4  = tid % 20;
    int r0  = tid / 20;

    float4 acc = make_float4(0.f, 0.f, 0.f, 0.f);
#pragma unroll
    for (int k = 0; k < 16; ++k) {
        float4 v = xp[(size_t)(r0 + k * 16) * 20 + c4];
        acc.x += v.x; acc.y += v.y; acc.z += v.z; acc.w += v.w;
    }

    __shared__ float red[320][4];
    red[tid][0] = acc.x; red[tid][1] = acc.y; red[tid][2] = acc.z; red[tid][3] = acc.w;
    __syncthreads();

    if (tid < DD) {
        int cc4 = tid >> 2, comp = tid & 3;
        float s = 0.f;
#pragma unroll
        for (int rr = 0; rr < 16; ++rr) s += red[cc4 + 20 * rr][comp];
        gpart[(b * NCHUNK + chunk) * DD + tid] = s;
    }
}

// ---------------------------------------------------------------------------
// K1.5: finalize ks[b][d] = (sum_c gpart) * KSCALE. 64 blocks x 80 threads.
// Removes the per-block 10KB gather K2 did in round 2 (84 MB of L2 traffic).
// ---------------------------------------------------------------------------
__global__ __launch_bounds__(128) void ksfin_kernel(const float* __restrict__ gpart,
                                                    float* __restrict__ ksf) {
    int b = blockIdx.x;
    int d = threadIdx.x;
    if (d < DD) {
        float s = 0.f;
#pragma unroll
        for (int c = 0; c < NCHUNK; ++c) s += gpart[(b * NCHUNK + c) * DD + d];
        ksf[b * DD + d] = s * KSCALE;
    }
}

// ---------------------------------------------------------------------------
// K2: out[b][h][t] = sum_d e_d*q_d / sum_d e_d, e = exp(tanh(q*ksum/sqrt(10)))
// (reference gate == softmax over size-1 axis == 1.0 -> dead)
// exp2-native math: sv = q*ks2 (ks2 pre-scaled by 2*log2e/sqrt10)
//   ex = exp2(-|sv|) = e^{-2|s|};  tanh_mag*log2e = log2e*(1-ex)/(1+ex)
//   e  = exp2(copysign(that, sv))
// LDS: xs stride 84 floats (336B, 16B aligned) -> q reads are ds_read_b128,
// lane bank pattern (84r) covers 32 banks per 8 lanes = conflict-free floor.
// 8192 blocks x 256 threads; stores 256B contiguous per wave per head.
// ---------------------------------------------------------------------------
#define XSTR 84
__global__ __launch_bounds__(256) void attn_kernel(const float* __restrict__ x,
                                                   const float* __restrict__ ksf,
                                                   float* __restrict__ out) {
    int chunk = blockIdx.x & 127;          // TT/64
    int b     = blockIdx.x >> 7;
    int t0    = chunk * 64;

    __shared__ float xs[64 * XSTR];
    __shared__ float ks[DD];

    const float4* xp = (const float4*)(x + ((size_t)b * TT + (size_t)t0) * DD);
    int tid = threadIdx.x;

    // stage: 1280 float4, 5 per thread, coalesced global -> LDS
#pragma unroll
    for (int k = 0; k < 5; ++k) {
        int f4  = tid + k * 256;
        int row = f4 / 20;
        int col = f4 % 20;
        *(float4*)&xs[row * XSTR + col * 4] = xp[f4];
    }
    if (tid < DD) ks[tid] = ksf[b * DD + tid];
    __syncthreads();

    int g = tid >> 6;                      // head pair 2g,2g+1 (wave-uniform)
    int r = tid & 63;
    int t = t0 + r;

    // load 20 q values as 5 x ds_read_b128
    float q[20];
    const float4* qrow = (const float4*)&xs[r * XSTR + g * 20];
#pragma unroll
    for (int k = 0; k < 5; ++k) {
        float4 v = qrow[k];
        q[4 * k] = v.x; q[4 * k + 1] = v.y; q[4 * k + 2] = v.z; q[4 * k + 3] = v.w;
    }

#pragma unroll
    for (int hh = 0; hh < 2; ++hh) {
        int h = g * 2 + hh;
        float esum = 0.f, eq = 0.f;
#pragma unroll
        for (int d = 0; d < 10; ++d) {
            float qv  = q[hh * 10 + d];
            float sv  = qv * ks[h * HD + d];
            float ex  = __builtin_amdgcn_exp2f(-fabsf(sv));     // e^{-2|s|}
            float num = __builtin_fmaf(-LOG2E, ex, LOG2E);      // log2e*(1-ex)
            float tm  = num * __builtin_amdgcn_rcpf(1.f + ex);  // log2e*tanh mag
            float e   = __builtin_amdgcn_exp2f(copysignf(tm, sv));
            esum += e;
            eq    = __builtin_fmaf(e, qv, eq);
        }
        out[((size_t)(b * NH + h)) * TT + t] = eq * __builtin_amdgcn_rcpf(esum);
    }
}

extern "C" void kernel_launch(void* const* d_in, const int* in_sizes, int n_in,
                              void* d_out, int out_size, void* d_ws, size_t ws_size,
                              hipStream_t stream) {
    const float* x = (const float*)d_in[0];
    // d_in[1] (w_proj) / d_in[2] (b_proj): dead (softmax over size-1 axis == 1)
    float* out   = (float*)d_out;
    float* gpart = (float*)d_ws;                        // 64*32*80 floats
    float* ksf   = gpart + BB * NCHUNK * DD;            // 64*80 floats

    ksum_kernel <<<dim3(BB * NCHUNK), dim3(320), 0, stream>>>(x, gpart);
    ksfin_kernel<<<dim3(BB),          dim3(128), 0, stream>>>(gpart, ksf);
    attn_kernel <<<dim3(BB * (TT/64)), dim3(256), 0, stream>>>(x, ksf, out);
}